// Round 7
// baseline (491.717 us; speedup 1.0000x reference)
//
#include <hip/hip_runtime.h>
#include <hip/hip_bf16.h>
#include <math.h>

#define CC   256
#define HW   (128*128)       // 16384
#define MAT  (CC*CC)         // 65536
#define NBH  2048
#define N0   4096
#define N1   8192
#define N2   16384

typedef __attribute__((ext_vector_type(8))) short bf16x8;
typedef __attribute__((ext_vector_type(4))) float f32x4;

// ---------------------------------------------------------------------------
// k_mats1: A[i][c][d] = M_i[c][d] = sum_o Wf[i,o,c]*Wp[i,o,d]   (bf16 rows 0..255)
//          E[i][o][c2] = sum_c3 Wfuse[o, i*C+c3]*Wo[i,c3,c2]    (fp32 temp)
// ---------------------------------------------------------------------------
__global__ __launch_bounds__(256) void k_mats1(
    const float* __restrict__ Wp, const float* __restrict__ Wf,
    const float* __restrict__ Wo, const float* __restrict__ Wfu,
    __hip_bfloat16* __restrict__ A, float* __restrict__ E)
{
    int idx = blockIdx.x;
    int t = threadIdx.x;
    if (idx < 3*CC) {
        int i = idx >> 8, c = idx & 255;
        const float* wf = Wf + (size_t)i*MAT;
        const float* wp = Wp + (size_t)i*MAT;
        float acc = 0.f;
        for (int o = 0; o < CC; ++o)
            acc += wf[o*CC + c] * wp[o*CC + t];
        A[(size_t)i*512*CC + (size_t)c*CC + t] = __float2bfloat16(acc);
    } else {
        idx -= 3*CC;
        int i = idx >> 8, o = idx & 255;
        const float* wo = Wo + (size_t)i*MAT;
        const float* wfu = Wfu + (size_t)o*(3*CC) + i*CC;
        float acc = 0.f;
        for (int c3 = 0; c3 < CC; ++c3)
            acc += wfu[c3] * wo[c3*CC + t];
        E[(size_t)i*MAT + (size_t)o*CC + t] = acc;
    }
}

// ---------------------------------------------------------------------------
// k_mats2: A[i][256+o][d] = V_i[o][d] = sum_c E_i[o][c]*Wp[i,c,d]   (bf16)
// ---------------------------------------------------------------------------
__global__ __launch_bounds__(256) void k_mats2(
    const float* __restrict__ Wp, const float* __restrict__ E,
    __hip_bfloat16* __restrict__ A)
{
    int idx = blockIdx.x;
    int i = idx >> 8, o = idx & 255;
    int t = threadIdx.x;
    const float* e = E + (size_t)i*MAT + (size_t)o*CC;
    const float* wp = Wp + (size_t)i*MAT;
    float acc = 0.f;
    for (int c = 0; c < CC; ++c)
        acc += e[c] * wp[c*CC + t];
    A[(size_t)i*512*CC + (size_t)(256+o)*CC + t] = __float2bfloat16(acc);
}

// ---------------------------------------------------------------------------
// k_poolA v3: 2 blocks per (b,c), each reads a 32 KB half-channel via 8 staged
// float4 loads (fits default VGPR budget). binsG[b][c][h][8] fp32 out.
// ---------------------------------------------------------------------------
__global__ __launch_bounds__(256) void k_poolA(
    const float* __restrict__ x, float* __restrict__ binsG)
{
    int blk = blockIdx.x;
    int bc = blk >> 1, half = blk & 1;
    int t = threadIdx.x;
    const float4* xp = (const float4*)(x + (size_t)bc*HW + half*8192) + t;
    __shared__ float bins[64][9];
    float4 v[8];
    #pragma unroll
    for (int i = 0; i < 8; ++i) v[i] = xp[i*256];
    int hb = t >> 5, bin = (t & 31) >> 2;
    #pragma unroll
    for (int i = 0; i < 8; ++i) {
        float s = v[i].x + v[i].y + v[i].z + v[i].w;
        s += __shfl_xor(s, 1);
        s += __shfl_xor(s, 2);           // sum of 16 w
        if ((t & 3) == 0) bins[i*8 + hb][bin] = s;
    }
    __syncthreads();
    if (t < 128) {
        int h = t >> 1, b0 = (t & 1) * 4;
        float4 o;
        o.x = bins[h][b0+0]; o.y = bins[h][b0+1];
        o.z = bins[h][b0+2]; o.w = bins[h][b0+3];
        ((float4*)binsG)[(size_t)bc*256 + half*128 + t] = o;
    }
}

// ---------------------------------------------------------------------------
// k_poolB: one bh per block, 256 thr (thread = c). Reads binsG[b][c][h][8],
// emits Bt (bf16): B0/B1/B2 rows, coalesced writes along c.
// ---------------------------------------------------------------------------
__global__ __launch_bounds__(256) void k_poolB(
    const float* __restrict__ binsG, __hip_bfloat16* __restrict__ Bt)
{
    int bh = blockIdx.x;
    int b = bh >> 7, h = bh & 127;
    int c = threadIdx.x;
    const float* g = binsG + (((size_t)b*256 + c)*128 + h)*8;
    float4 lo = *(const float4*)(g);
    float4 hi = *(const float4*)(g + 4);
    float b8[8] = {lo.x, lo.y, lo.z, lo.w, hi.x, hi.y, hi.z, hi.w};

    __hip_bfloat16* B0 = Bt;
    __hip_bfloat16* B1 = Bt + (size_t)N0*CC;
    __hip_bfloat16* B2 = Bt + (size_t)(N0+N1)*CC;
    B0[((size_t)bh*2 + 0)*CC + c] = __float2bfloat16((b8[0]+b8[1]+b8[2]+b8[3]) * (1.f/64.f));
    B0[((size_t)bh*2 + 1)*CC + c] = __float2bfloat16((b8[4]+b8[5]+b8[6]+b8[7]) * (1.f/64.f));
    #pragma unroll
    for (int j = 0; j < 4; ++j)
        B1[((size_t)bh*4 + j)*CC + c] = __float2bfloat16((b8[2*j]+b8[2*j+1]) * (1.f/32.f));
    #pragma unroll
    for (int j = 0; j < 8; ++j)
        B2[((size_t)bh*8 + j)*CC + c] = __float2bfloat16(b8[j] * (1.f/16.f));
}

// ---------------------------------------------------------------------------
// k_gemm: 1792 blocks x 128 thr. Block tile 128x64, wave tile 64x64.
// Epilogue scatters into Cc[bh][512][16] fp32 (rows 0..255 mp, 256..511 vp).
// ---------------------------------------------------------------------------
__global__ __launch_bounds__(128) void k_gemm(
    const __hip_bfloat16* __restrict__ A,
    const __hip_bfloat16* __restrict__ Bt,
    float* __restrict__ Cc)
{
    int blk = blockIdx.x;
    int br, lb, LP, poff;
    if (blk < 256)      { br = 0; lb = blk;       LP = 1; poff = 0; }
    else if (blk < 768) { br = 1; lb = blk - 256; LP = 2; poff = 2; }
    else                { br = 2; lb = blk - 768; LP = 3; poff = 6; }
    size_t aoff  = (size_t)br*512*CC;
    size_t btoff = (br == 0) ? 0 : (br == 1 ? (size_t)N0*CC : (size_t)(N0+N1)*CC);
    const __hip_bfloat16* Ab = A  + aoff;
    const __hip_bfloat16* Bb = Bt + btoff;

    int rb = lb & 3, cb = lb >> 2;
    int wv = threadIdx.x >> 6, lane = threadIdx.x & 63;
    int row0 = rb*128 + wv*64;
    int col0 = cb*64;
    int lr = lane & 15, lk = (lane >> 4) * 8;

    f32x4 acc[4][4] = {};
    for (int kk = 0; kk < CC; kk += 32) {
        bf16x8 af[4], bfr[4];
        #pragma unroll
        for (int m = 0; m < 4; ++m)
            af[m] = *reinterpret_cast<const bf16x8*>(Ab + (size_t)(row0 + m*16 + lr)*CC + kk + lk);
        #pragma unroll
        for (int n = 0; n < 4; ++n)
            bfr[n] = *reinterpret_cast<const bf16x8*>(Bb + (size_t)(col0 + n*16 + lr)*CC + kk + lk);
        #pragma unroll
        for (int m = 0; m < 4; ++m)
            #pragma unroll
            for (int n = 0; n < 4; ++n)
                acc[m][n] = __builtin_amdgcn_mfma_f32_16x16x32_bf16(af[m], bfr[n], acc[m][n], 0, 0, 0);
    }

    int cr = (lane >> 4) * 4, ccol = lane & 15;
    int pm = (1 << LP) - 1;
    #pragma unroll
    for (int m = 0; m < 4; ++m) {
        #pragma unroll
        for (int n = 0; n < 4; ++n) {
            int colg = col0 + n*16 + ccol;
            int bh = colg >> LP, p = colg & pm;
            float* dst = Cc + (size_t)bh*8192 + poff + p;
            #pragma unroll
            for (int j = 0; j < 4; ++j) {
                int r = row0 + m*16 + cr + j;
                dst[r*16] = acc[m][n][j];
            }
        }
    }
}

// ---------------------------------------------------------------------------
// k_main v7: one bh per block, 4 waves = c (mod 4). Lane owns a w-pair.
// Wave caches ALL 64 of its channels in registers (xc[64], 128 VGPR):
// pass A = 64 independent loads + FMA; pass B = pure FMA + stores (no loads).
// launch_bounds(256,2) -> 256 VGPR cap, 2 waves/SIMD.
// ---------------------------------------------------------------------------
template<int L>
__device__ __forceinline__ void softmax2(float2* a) {
    float mx = a[0].x, my = a[0].y;
    #pragma unroll
    for (int j = 1; j < L; ++j) { mx = fmaxf(mx, a[j].x); my = fmaxf(my, a[j].y); }
    float sx = 0.f, sy = 0.f;
    #pragma unroll
    for (int j = 0; j < L; ++j) {
        a[j].x = __expf(a[j].x - mx); sx += a[j].x;
        a[j].y = __expf(a[j].y - my); sy += a[j].y;
    }
    float rx = 1.f / sx, ry = 1.f / sy;
    #pragma unroll
    for (int j = 0; j < L; ++j) { a[j].x *= rx; a[j].y *= ry; }
}

__global__ __launch_bounds__(256, 2) void k_main(
    const float* __restrict__ x, const float* __restrict__ Cc,
    float* __restrict__ out)
{
    int bh = blockIdx.x;
    int b = bh >> 7, h = bh & 127;
    int t = threadIdx.x;
    int lane = t & 63;
    int wv = __builtin_amdgcn_readfirstlane(t >> 6);   // 0..3
    const float* Cb = Cc + (size_t)bh * 8192;
    const float2* x2 = (const float2*)x + ((size_t)b*CC)*(HW/2) + h*64 + lane;
    float2*       o2 = (float2*)out     + ((size_t)b*CC)*(HW/2) + h*64 + lane;
    __shared__ float att_sx[2][64][15];
    __shared__ float att_sy[2][64][15];

    float2 xc[64];
    #pragma unroll
    for (int j = 0; j < 64; ++j)
        xc[j] = x2[(size_t)(j*4 + wv)*(HW/2)];

    float2 att[14];
    #pragma unroll
    for (int p = 0; p < 14; ++p) att[p] = make_float2(0.f, 0.f);

    #pragma unroll
    for (int j = 0; j < 64; ++j) {
        int c = j*4 + wv;
        const float* mp = Cb + c*16;                   // wave-uniform s_load
        #pragma unroll
        for (int p = 0; p < 14; ++p) {
            att[p].x += xc[j].x * mp[p];
            att[p].y += xc[j].y * mp[p];
        }
    }

    // ---- reduce across 4 waves ----
    if (wv >= 2) {
        #pragma unroll
        for (int p = 0; p < 14; ++p) {
            att_sx[wv-2][lane][p] = att[p].x;
            att_sy[wv-2][lane][p] = att[p].y;
        }
    }
    __syncthreads();
    if (wv < 2) {
        #pragma unroll
        for (int p = 0; p < 14; ++p) {
            att[p].x += att_sx[wv][lane][p];
            att[p].y += att_sy[wv][lane][p];
        }
        if (wv == 1) {
            #pragma unroll
            for (int p = 0; p < 14; ++p) {
                att_sx[1][lane][p] = att[p].x;
                att_sy[1][lane][p] = att[p].y;
            }
        }
    }
    __syncthreads();
    if (wv == 0) {
        #pragma unroll
        for (int p = 0; p < 14; ++p) {
            att[p].x = (att[p].x + att_sx[1][lane][p]) * 0.0625f;
            att[p].y = (att[p].y + att_sy[1][lane][p]) * 0.0625f;
        }
        softmax2<2>(att + 0);
        softmax2<4>(att + 2);
        softmax2<8>(att + 6);
        #pragma unroll
        for (int p = 0; p < 14; ++p) {
            att_sx[0][lane][p] = att[p].x;
            att_sy[0][lane][p] = att[p].y;
        }
    }
    __syncthreads();
    #pragma unroll
    for (int p = 0; p < 14; ++p) {
        att[p].x = att_sx[0][lane][p];
        att[p].y = att_sy[0][lane][p];
    }

    // ---- pass B: out = xc + att.vp, no global loads ----
    #pragma unroll
    for (int j = 0; j < 64; ++j) {
        int o = j*4 + wv;
        const float* vp = Cb + (256 + o)*16;           // wave-uniform s_load
        float2 acc = xc[j];
        #pragma unroll
        for (int p = 0; p < 14; ++p) {
            acc.x += att[p].x * vp[p];
            acc.y += att[p].y * vp[p];
        }
        o2[(size_t)o*(HW/2)] = acc;
    }
}

// ---------------------------------------------------------------------------
extern "C" void kernel_launch(void* const* d_in, const int* in_sizes, int n_in,
                              void* d_out, int out_size, void* d_ws, size_t ws_size,
                              hipStream_t stream)
{
    (void)in_sizes; (void)n_in; (void)out_size; (void)ws_size;
    const float* x   = (const float*)d_in[0];
    const float* Wp  = (const float*)d_in[1];
    const float* Wf  = (const float*)d_in[2];
    const float* Wo  = (const float*)d_in[3];
    const float* Wfu = (const float*)d_in[4];
    float* out = (float*)d_out;

    // workspace layout (bytes):
    //   E     fp32 3*MAT     @ 0         =   786432
    //   A     bf16 3*512*256 @ 786432    =   786432
    //   Bt    bf16 28672*256 @ 1572864   = 14680064
    //   Cc    fp32 2048*8192 @ 16252928  = 67108864   (binsG aliases Cc: 16.8 MB,
    //                                                  consumed by poolB before k_gemm writes Cc)
    char* wsb = (char*)d_ws;
    float*          E     = (float*)wsb;
    __hip_bfloat16* A     = (__hip_bfloat16*)(wsb + 786432);
    __hip_bfloat16* Bt    = (__hip_bfloat16*)(wsb + 1572864);
    float*          Cc    = (float*)(wsb + 16252928);
    float*          binsG = Cc;

    k_mats1<<<dim3(6*CC),  dim3(256), 0, stream>>>(Wp, Wf, Wo, Wfu, A, E);
    k_mats2<<<dim3(3*CC),  dim3(256), 0, stream>>>(Wp, E, A);
    k_poolA<<<dim3(8192),  dim3(256), 0, stream>>>(x, binsG);
    k_poolB<<<dim3(NBH),   dim3(256), 0, stream>>>(binsG, Bt);
    k_gemm <<<dim3(1792),  dim3(128), 0, stream>>>(A, Bt, Cc);
    k_main <<<dim3(NBH),   dim3(256), 0, stream>>>(x, Cc, out);
}

// Round 8
// 334.057 us; speedup vs baseline: 1.4720x; 1.4720x over previous
//
#include <hip/hip_runtime.h>
#include <hip/hip_bf16.h>
#include <math.h>
#include <stdint.h>

#define CC   256
#define HW   (128*128)       // 16384
#define MAT  (CC*CC)         // 65536
#define NBH  2048
#define N0   4096
#define N1   8192
#define N2   16384

typedef __attribute__((ext_vector_type(8))) short bf16x8;
typedef __attribute__((ext_vector_type(4))) float f32x4;
typedef __attribute__((address_space(3))) uint32_t lds_u32_t;
typedef __attribute__((address_space(1))) const uint32_t glb_u32_t;

// ---------------------------------------------------------------------------
// k_mats1: A[i][c][d] = M_i[c][d] = sum_o Wf[i,o,c]*Wp[i,o,d]   (bf16 rows 0..255)
//          E[i][o][c2] = sum_c3 Wfuse[o, i*C+c3]*Wo[i,c3,c2]    (fp32 temp)
// ---------------------------------------------------------------------------
__global__ __launch_bounds__(256) void k_mats1(
    const float* __restrict__ Wp, const float* __restrict__ Wf,
    const float* __restrict__ Wo, const float* __restrict__ Wfu,
    __hip_bfloat16* __restrict__ A, float* __restrict__ E)
{
    int idx = blockIdx.x;
    int t = threadIdx.x;
    if (idx < 3*CC) {
        int i = idx >> 8, c = idx & 255;
        const float* wf = Wf + (size_t)i*MAT;
        const float* wp = Wp + (size_t)i*MAT;
        float acc = 0.f;
        for (int o = 0; o < CC; ++o)
            acc += wf[o*CC + c] * wp[o*CC + t];
        A[(size_t)i*512*CC + (size_t)c*CC + t] = __float2bfloat16(acc);
    } else {
        idx -= 3*CC;
        int i = idx >> 8, o = idx & 255;
        const float* wo = Wo + (size_t)i*MAT;
        const float* wfu = Wfu + (size_t)o*(3*CC) + i*CC;
        float acc = 0.f;
        for (int c3 = 0; c3 < CC; ++c3)
            acc += wfu[c3] * wo[c3*CC + t];
        E[(size_t)i*MAT + (size_t)o*CC + t] = acc;
    }
}

// ---------------------------------------------------------------------------
// k_mats2: A[i][256+o][d] = V_i[o][d] = sum_c E_i[o][c]*Wp[i,c,d]   (bf16)
// ---------------------------------------------------------------------------
__global__ __launch_bounds__(256) void k_mats2(
    const float* __restrict__ Wp, const float* __restrict__ E,
    __hip_bfloat16* __restrict__ A)
{
    int idx = blockIdx.x;
    int i = idx >> 8, o = idx & 255;
    int t = threadIdx.x;
    const float* e = E + (size_t)i*MAT + (size_t)o*CC;
    const float* wp = Wp + (size_t)i*MAT;
    float acc = 0.f;
    for (int c = 0; c < CC; ++c)
        acc += e[c] * wp[c*CC + t];
    A[(size_t)i*512*CC + (size_t)(256+o)*CC + t] = __float2bfloat16(acc);
}

// ---------------------------------------------------------------------------
// k_poolA: one (b,c) per block, 16-deep float4 staging (launch_bounds 256,4
// gives the 128-VGPR budget the staging needs). binsG[b][c][h][8] fp32 out.
// ---------------------------------------------------------------------------
__global__ __launch_bounds__(256, 4) void k_poolA(
    const float* __restrict__ x, float* __restrict__ binsG)
{
    int bc = blockIdx.x;                 // b*256 + c
    int t = threadIdx.x;
    const float4* xp = (const float4*)(x + (size_t)bc*HW) + t;
    __shared__ float bins[128][9];
    float4 v[16];
    #pragma unroll
    for (int i = 0; i < 16; ++i) v[i] = xp[i*256];
    int hb = t >> 5, bin = (t & 31) >> 2;
    #pragma unroll
    for (int i = 0; i < 16; ++i) {
        float s = v[i].x + v[i].y + v[i].z + v[i].w;
        s += __shfl_xor(s, 1);
        s += __shfl_xor(s, 2);           // sum of 16 w
        if ((t & 3) == 0) bins[i*8 + hb][bin] = s;
    }
    __syncthreads();
    int h = t >> 1, b0 = (t & 1) * 4;
    float4 o;
    o.x = bins[h][b0+0]; o.y = bins[h][b0+1];
    o.z = bins[h][b0+2]; o.w = bins[h][b0+3];
    ((float4*)binsG)[(size_t)bc*256 + t] = o;
}

// ---------------------------------------------------------------------------
// k_poolB: one bh per block, 256 thr (thread = c). Reads binsG[b][c][h][8],
// emits Bt (bf16): B0/B1/B2 rows, coalesced writes along c.
// ---------------------------------------------------------------------------
__global__ __launch_bounds__(256) void k_poolB(
    const float* __restrict__ binsG, __hip_bfloat16* __restrict__ Bt)
{
    int bh = blockIdx.x;
    int b = bh >> 7, h = bh & 127;
    int c = threadIdx.x;
    const float* g = binsG + (((size_t)b*256 + c)*128 + h)*8;
    float4 lo = *(const float4*)(g);
    float4 hi = *(const float4*)(g + 4);
    float b8[8] = {lo.x, lo.y, lo.z, lo.w, hi.x, hi.y, hi.z, hi.w};

    __hip_bfloat16* B0 = Bt;
    __hip_bfloat16* B1 = Bt + (size_t)N0*CC;
    __hip_bfloat16* B2 = Bt + (size_t)(N0+N1)*CC;
    B0[((size_t)bh*2 + 0)*CC + c] = __float2bfloat16((b8[0]+b8[1]+b8[2]+b8[3]) * (1.f/64.f));
    B0[((size_t)bh*2 + 1)*CC + c] = __float2bfloat16((b8[4]+b8[5]+b8[6]+b8[7]) * (1.f/64.f));
    #pragma unroll
    for (int j = 0; j < 4; ++j)
        B1[((size_t)bh*4 + j)*CC + c] = __float2bfloat16((b8[2*j]+b8[2*j+1]) * (1.f/32.f));
    #pragma unroll
    for (int j = 0; j < 8; ++j)
        B2[((size_t)bh*8 + j)*CC + c] = __float2bfloat16(b8[j] * (1.f/16.f));
}

// ---------------------------------------------------------------------------
// k_gemm: 1792 blocks x 128 thr. Block tile 128x64, wave tile 64x64.
// Epilogue scatters BF16 into Cc[bh][512][16] (rows 0..255 mp, 256..511 vp).
// ---------------------------------------------------------------------------
__global__ __launch_bounds__(128) void k_gemm(
    const __hip_bfloat16* __restrict__ A,
    const __hip_bfloat16* __restrict__ Bt,
    __hip_bfloat16* __restrict__ Cc)
{
    int blk = blockIdx.x;
    int br, lb, LP, poff;
    if (blk < 256)      { br = 0; lb = blk;       LP = 1; poff = 0; }
    else if (blk < 768) { br = 1; lb = blk - 256; LP = 2; poff = 2; }
    else                { br = 2; lb = blk - 768; LP = 3; poff = 6; }
    size_t aoff  = (size_t)br*512*CC;
    size_t btoff = (br == 0) ? 0 : (br == 1 ? (size_t)N0*CC : (size_t)(N0+N1)*CC);
    const __hip_bfloat16* Ab = A  + aoff;
    const __hip_bfloat16* Bb = Bt + btoff;

    int rb = lb & 3, cb = lb >> 2;
    int wv = threadIdx.x >> 6, lane = threadIdx.x & 63;
    int row0 = rb*128 + wv*64;
    int col0 = cb*64;
    int lr = lane & 15, lk = (lane >> 4) * 8;

    f32x4 acc[4][4] = {};
    for (int kk = 0; kk < CC; kk += 32) {
        bf16x8 af[4], bfr[4];
        #pragma unroll
        for (int m = 0; m < 4; ++m)
            af[m] = *reinterpret_cast<const bf16x8*>(Ab + (size_t)(row0 + m*16 + lr)*CC + kk + lk);
        #pragma unroll
        for (int n = 0; n < 4; ++n)
            bfr[n] = *reinterpret_cast<const bf16x8*>(Bb + (size_t)(col0 + n*16 + lr)*CC + kk + lk);
        #pragma unroll
        for (int m = 0; m < 4; ++m)
            #pragma unroll
            for (int n = 0; n < 4; ++n)
                acc[m][n] = __builtin_amdgcn_mfma_f32_16x16x32_bf16(af[m], bfr[n], acc[m][n], 0, 0, 0);
    }

    int cr = (lane >> 4) * 4, ccol = lane & 15;
    int pm = (1 << LP) - 1;
    #pragma unroll
    for (int m = 0; m < 4; ++m) {
        #pragma unroll
        for (int n = 0; n < 4; ++n) {
            int colg = col0 + n*16 + ccol;
            int bh = colg >> LP, p = colg & pm;
            __hip_bfloat16* dst = Cc + (size_t)bh*8192 + poff + p;
            #pragma unroll
            for (int j = 0; j < 4; ++j) {
                int r = row0 + m*16 + cr + j;
                dst[r*16] = __float2bfloat16(acc[m][n][j]);
            }
        }
    }
}

// ---------------------------------------------------------------------------
// k_main v8: one bh per block, 4 waves. x streamed via global_load_lds into
// a triple-buffered 32-channel LDS tile, prefetch distance 2, counted vmcnt,
// raw s_barrier (no queue drain). 16 tiles: 8 = logits pass, 8 = PV pass
// (residual read from LDS). Weights = bf16 Cc rows via batched s_loads,
// unpacked with shift/mask (SALU). att reduce/softmax between passes.
// ---------------------------------------------------------------------------
template<int L>
__device__ __forceinline__ void softmax2(float2* a) {
    float mx = a[0].x, my = a[0].y;
    #pragma unroll
    for (int j = 1; j < L; ++j) { mx = fmaxf(mx, a[j].x); my = fmaxf(my, a[j].y); }
    float sx = 0.f, sy = 0.f;
    #pragma unroll
    for (int j = 0; j < L; ++j) {
        a[j].x = __expf(a[j].x - mx); sx += a[j].x;
        a[j].y = __expf(a[j].y - my); sy += a[j].y;
    }
    float rx = 1.f / sx, ry = 1.f / sy;
    #pragma unroll
    for (int j = 0; j < L; ++j) { a[j].x *= rx; a[j].y *= ry; }
}

__global__ __launch_bounds__(256, 4) void k_main(
    const float* __restrict__ x, const __hip_bfloat16* __restrict__ Cc,
    float* __restrict__ out)
{
    int bh = blockIdx.x;
    int b = bh >> 7, h = bh & 127;
    int t = threadIdx.x;
    int lane = t & 63;
    int wv = __builtin_amdgcn_readfirstlane(t >> 6);   // 0..3, wave-uniform
    const uint32_t* Cb = (const uint32_t*)(Cc + (size_t)bh*8192); // 8 dw / row
    const float* xg = x  + ((size_t)b*CC)*HW + h*128;  // + c*HW + w
    float*       og = out + ((size_t)b*CC)*HW + h*128;

    __shared__ float xbuf[3][32*128];                  // 49152 B
    __shared__ float att_sx[2][64][15];                // 7680 B
    __shared__ float att_sy[2][64][15];                // 7680 B

    float2 att[14];
    #pragma unroll
    for (int p = 0; p < 14; ++p) att[p] = make_float2(0.f, 0.f);

    // stage tile tt (channels (tt&7)*32) into xbuf[tt%3]; 4 DMA per wave
    auto STAGE = [&](int tt) {
        int cb = (tt & 7) * 32;
        float* bufp = xbuf[tt % 3];
        #pragma unroll
        for (int q = 0; q < 4; ++q) {
            int c0 = cb + wv*8 + q*2;
            const float* gp = xg + (size_t)(c0 + (lane >> 5))*HW + (lane & 31)*4;
            float* lp = &bufp[(wv*8 + q*2)*128];
            __builtin_amdgcn_global_load_lds((glb_u32_t*)gp, (lds_u32_t*)lp, 16, 0, 0);
        }
    };

    STAGE(0);
    STAGE(1);

    #pragma unroll 1
    for (int tt = 0; tt < 16; ++tt) {
        if (tt < 15) asm volatile("s_waitcnt vmcnt(4)" ::: "memory");
        else         asm volatile("s_waitcnt vmcnt(0)" ::: "memory");
        __builtin_amdgcn_s_barrier();
        __builtin_amdgcn_sched_barrier(0);

        if (tt == 8) {
            // ---- cross-wave att reduce + softmax (pass boundary) ----
            if (wv >= 2) {
                #pragma unroll
                for (int p = 0; p < 14; ++p) {
                    att_sx[wv-2][lane][p] = att[p].x;
                    att_sy[wv-2][lane][p] = att[p].y;
                }
            }
            asm volatile("s_waitcnt lgkmcnt(0)" ::: "memory");
            __builtin_amdgcn_s_barrier();
            __builtin_amdgcn_sched_barrier(0);
            if (wv < 2) {
                #pragma unroll
                for (int p = 0; p < 14; ++p) {
                    att[p].x += att_sx[wv][lane][p];
                    att[p].y += att_sy[wv][lane][p];
                }
                if (wv == 1) {
                    #pragma unroll
                    for (int p = 0; p < 14; ++p) {
                        att_sx[1][lane][p] = att[p].x;
                        att_sy[1][lane][p] = att[p].y;
                    }
                }
            }
            asm volatile("s_waitcnt lgkmcnt(0)" ::: "memory");
            __builtin_amdgcn_s_barrier();
            __builtin_amdgcn_sched_barrier(0);
            if (wv == 0) {
                #pragma unroll
                for (int p = 0; p < 14; ++p) {
                    att[p].x = (att[p].x + att_sx[1][lane][p]) * 0.0625f;
                    att[p].y = (att[p].y + att_sy[1][lane][p]) * 0.0625f;
                }
                softmax2<2>(att + 0);
                softmax2<4>(att + 2);
                softmax2<8>(att + 6);
                #pragma unroll
                for (int p = 0; p < 14; ++p) {
                    att_sx[0][lane][p] = att[p].x;
                    att_sy[0][lane][p] = att[p].y;
                }
            }
            asm volatile("s_waitcnt lgkmcnt(0)" ::: "memory");
            __builtin_amdgcn_s_barrier();
            __builtin_amdgcn_sched_barrier(0);
            #pragma unroll
            for (int p = 0; p < 14; ++p) {
                att[p].x = att_sx[0][lane][p];
                att[p].y = att_sy[0][lane][p];
            }
        }

        if (tt + 2 < 16) STAGE(tt + 2);

        // ---- consume tile tt ----
        {
            int cb = (tt & 7) * 32;
            bool passB = (tt >= 8);
            const float* xb = &xbuf[tt % 3][(wv*8)*128];
            int crow = (passB ? 256 : 0) + cb + wv*8;
            const uint32_t* wr = Cb + (size_t)crow*8;
            #pragma unroll
            for (int half = 0; half < 2; ++half) {
                uint32_t u[4][7];
                #pragma unroll
                for (int q = 0; q < 4; ++q)
                    #pragma unroll
                    for (int j = 0; j < 7; ++j)
                        u[q][j] = wr[(half*4 + q)*8 + j];   // wave-uniform s_loads
                #pragma unroll
                for (int q = 0; q < 4; ++q) {
                    int qq = half*4 + q;
                    float2 xv = *(const float2*)&xb[qq*128 + lane*2];
                    if (!passB) {
                        #pragma unroll
                        for (int j = 0; j < 7; ++j) {
                            float mlo = __uint_as_float(u[q][j] << 16);
                            float mhi = __uint_as_float(u[q][j] & 0xFFFF0000u);
                            att[2*j].x   += xv.x * mlo;  att[2*j].y   += xv.y * mlo;
                            att[2*j+1].x += xv.x * mhi;  att[2*j+1].y += xv.y * mhi;
                        }
                    } else {
                        float2 acc = xv;                    // residual (exact fp32)
                        #pragma unroll
                        for (int j = 0; j < 7; ++j) {
                            float vlo = __uint_as_float(u[q][j] << 16);
                            float vhi = __uint_as_float(u[q][j] & 0xFFFF0000u);
                            acc.x += att[2*j].x * vlo;   acc.y += att[2*j].y * vlo;
                            acc.x += att[2*j+1].x * vhi; acc.y += att[2*j+1].y * vhi;
                        }
                        int o = cb + wv*8 + qq;
                        *(float2*)&og[(size_t)o*HW + lane*2] = acc;
                    }
                }
            }
        }
    }
}

// ---------------------------------------------------------------------------
extern "C" void kernel_launch(void* const* d_in, const int* in_sizes, int n_in,
                              void* d_out, int out_size, void* d_ws, size_t ws_size,
                              hipStream_t stream)
{
    (void)in_sizes; (void)n_in; (void)out_size; (void)ws_size;
    const float* x   = (const float*)d_in[0];
    const float* Wp  = (const float*)d_in[1];
    const float* Wf  = (const float*)d_in[2];
    const float* Wo  = (const float*)d_in[3];
    const float* Wfu = (const float*)d_in[4];
    float* out = (float*)d_out;

    // workspace layout (bytes):
    //   E     fp32 3*MAT          @ 0         =   786432
    //   A     bf16 3*512*256      @ 786432    =   786432
    //   Bt    bf16 28672*256      @ 1572864   = 14680064
    //   Cc    bf16 2048*512*16    @ 16252928  = 33554432
    //   (binsG fp32 16.8 MB aliases Cc: consumed by poolB before k_gemm)
    char* wsb = (char*)d_ws;
    float*          E     = (float*)wsb;
    __hip_bfloat16* A     = (__hip_bfloat16*)(wsb + 786432);
    __hip_bfloat16* Bt    = (__hip_bfloat16*)(wsb + 1572864);
    __hip_bfloat16* Cc    = (__hip_bfloat16*)(wsb + 16252928);
    float*          binsG = (float*)(wsb + 16252928);

    k_mats1<<<dim3(6*CC),  dim3(256), 0, stream>>>(Wp, Wf, Wo, Wfu, A, E);
    k_mats2<<<dim3(3*CC),  dim3(256), 0, stream>>>(Wp, E, A);
    k_poolA<<<dim3(4096),  dim3(256), 0, stream>>>(x, binsG);
    k_poolB<<<dim3(NBH),   dim3(256), 0, stream>>>(binsG, Bt);
    k_gemm <<<dim3(1792),  dim3(128), 0, stream>>>(A, Bt, Cc);
    k_main <<<dim3(NBH),   dim3(256), 0, stream>>>(x, Cc, out);
}

// Round 9
// 326.830 us; speedup vs baseline: 1.5045x; 1.0221x over previous
//
#include <hip/hip_runtime.h>
#include <hip/hip_bf16.h>
#include <math.h>
#include <stdint.h>

#define CC   256
#define HW   (128*128)       // 16384
#define MAT  (CC*CC)         // 65536
#define NBH  2048
#define N0   4096
#define N1   8192
#define N2   16384

typedef __attribute__((ext_vector_type(8))) short bf16x8;
typedef __attribute__((ext_vector_type(4))) float f32x4;
typedef __attribute__((address_space(3))) uint32_t lds_u32_t;
typedef __attribute__((address_space(1))) const uint32_t glb_u32_t;

// ---------------------------------------------------------------------------
// k_mats1: A[i][c][d] = M_i[c][d] = sum_o Wf[i,o,c]*Wp[i,o,d]   (bf16 rows 0..255)
//          E[i][o][c2] = sum_c3 Wfuse[o, i*C+c3]*Wo[i,c3,c2]    (fp32 temp)
// ---------------------------------------------------------------------------
__global__ __launch_bounds__(256) void k_mats1(
    const float* __restrict__ Wp, const float* __restrict__ Wf,
    const float* __restrict__ Wo, const float* __restrict__ Wfu,
    __hip_bfloat16* __restrict__ A, float* __restrict__ E)
{
    int idx = blockIdx.x;
    int t = threadIdx.x;
    if (idx < 3*CC) {
        int i = idx >> 8, c = idx & 255;
        const float* wf = Wf + (size_t)i*MAT;
        const float* wp = Wp + (size_t)i*MAT;
        float acc = 0.f;
        for (int o = 0; o < CC; ++o)
            acc += wf[o*CC + c] * wp[o*CC + t];
        A[(size_t)i*512*CC + (size_t)c*CC + t] = __float2bfloat16(acc);
    } else {
        idx -= 3*CC;
        int i = idx >> 8, o = idx & 255;
        const float* wo = Wo + (size_t)i*MAT;
        const float* wfu = Wfu + (size_t)o*(3*CC) + i*CC;
        float acc = 0.f;
        for (int c3 = 0; c3 < CC; ++c3)
            acc += wfu[c3] * wo[c3*CC + t];
        E[(size_t)i*MAT + (size_t)o*CC + t] = acc;
    }
}

// ---------------------------------------------------------------------------
// k_mats2: A[i][256+o][d] = V_i[o][d] = sum_c E_i[o][c]*Wp[i,c,d]   (bf16)
// ---------------------------------------------------------------------------
__global__ __launch_bounds__(256) void k_mats2(
    const float* __restrict__ Wp, const float* __restrict__ E,
    __hip_bfloat16* __restrict__ A)
{
    int idx = blockIdx.x;
    int i = idx >> 8, o = idx & 255;
    int t = threadIdx.x;
    const float* e = E + (size_t)i*MAT + (size_t)o*CC;
    const float* wp = Wp + (size_t)i*MAT;
    float acc = 0.f;
    for (int c = 0; c < CC; ++c)
        acc += e[c] * wp[c*CC + t];
    A[(size_t)i*512*CC + (size_t)(256+o)*CC + t] = __float2bfloat16(acc);
}

// ---------------------------------------------------------------------------
// k_poolA: one (b,c) per block, 16-deep float4 staging (launch_bounds 256,4
// gives the 128-VGPR budget the staging needs). binsG[b][c][h][8] fp32 out.
// ---------------------------------------------------------------------------
__global__ __launch_bounds__(256, 4) void k_poolA(
    const float* __restrict__ x, float* __restrict__ binsG)
{
    int bc = blockIdx.x;                 // b*256 + c
    int t = threadIdx.x;
    const float4* xp = (const float4*)(x + (size_t)bc*HW) + t;
    __shared__ float bins[128][9];
    float4 v[16];
    #pragma unroll
    for (int i = 0; i < 16; ++i) v[i] = xp[i*256];
    int hb = t >> 5, bin = (t & 31) >> 2;
    #pragma unroll
    for (int i = 0; i < 16; ++i) {
        float s = v[i].x + v[i].y + v[i].z + v[i].w;
        s += __shfl_xor(s, 1);
        s += __shfl_xor(s, 2);           // sum of 16 w
        if ((t & 3) == 0) bins[i*8 + hb][bin] = s;
    }
    __syncthreads();
    int h = t >> 1, b0 = (t & 1) * 4;
    float4 o;
    o.x = bins[h][b0+0]; o.y = bins[h][b0+1];
    o.z = bins[h][b0+2]; o.w = bins[h][b0+3];
    ((float4*)binsG)[(size_t)bc*256 + t] = o;
}

// ---------------------------------------------------------------------------
// k_poolB: one bh per block, 256 thr (thread = c). Reads binsG[b][c][h][8],
// emits Bt (bf16): B0/B1/B2 rows, coalesced writes along c.
// ---------------------------------------------------------------------------
__global__ __launch_bounds__(256) void k_poolB(
    const float* __restrict__ binsG, __hip_bfloat16* __restrict__ Bt)
{
    int bh = blockIdx.x;
    int b = bh >> 7, h = bh & 127;
    int c = threadIdx.x;
    const float* g = binsG + (((size_t)b*256 + c)*128 + h)*8;
    float4 lo = *(const float4*)(g);
    float4 hi = *(const float4*)(g + 4);
    float b8[8] = {lo.x, lo.y, lo.z, lo.w, hi.x, hi.y, hi.z, hi.w};

    __hip_bfloat16* B0 = Bt;
    __hip_bfloat16* B1 = Bt + (size_t)N0*CC;
    __hip_bfloat16* B2 = Bt + (size_t)(N0+N1)*CC;
    B0[((size_t)bh*2 + 0)*CC + c] = __float2bfloat16((b8[0]+b8[1]+b8[2]+b8[3]) * (1.f/64.f));
    B0[((size_t)bh*2 + 1)*CC + c] = __float2bfloat16((b8[4]+b8[5]+b8[6]+b8[7]) * (1.f/64.f));
    #pragma unroll
    for (int j = 0; j < 4; ++j)
        B1[((size_t)bh*4 + j)*CC + c] = __float2bfloat16((b8[2*j]+b8[2*j+1]) * (1.f/32.f));
    #pragma unroll
    for (int j = 0; j < 8; ++j)
        B2[((size_t)bh*8 + j)*CC + c] = __float2bfloat16(b8[j] * (1.f/16.f));
}

// ---------------------------------------------------------------------------
// k_gemm: 1792 blocks x 128 thr. Block tile 128x64, wave tile 64x64.
// Epilogue scatters BF16 into Cc[bh][512][16] (rows 0..255 mp, 256..511 vp).
// ---------------------------------------------------------------------------
__global__ __launch_bounds__(128) void k_gemm(
    const __hip_bfloat16* __restrict__ A,
    const __hip_bfloat16* __restrict__ Bt,
    __hip_bfloat16* __restrict__ Cc)
{
    int blk = blockIdx.x;
    int br, lb, LP, poff;
    if (blk < 256)      { br = 0; lb = blk;       LP = 1; poff = 0; }
    else if (blk < 768) { br = 1; lb = blk - 256; LP = 2; poff = 2; }
    else                { br = 2; lb = blk - 768; LP = 3; poff = 6; }
    size_t aoff  = (size_t)br*512*CC;
    size_t btoff = (br == 0) ? 0 : (br == 1 ? (size_t)N0*CC : (size_t)(N0+N1)*CC);
    const __hip_bfloat16* Ab = A  + aoff;
    const __hip_bfloat16* Bb = Bt + btoff;

    int rb = lb & 3, cb = lb >> 2;
    int wv = threadIdx.x >> 6, lane = threadIdx.x & 63;
    int row0 = rb*128 + wv*64;
    int col0 = cb*64;
    int lr = lane & 15, lk = (lane >> 4) * 8;

    f32x4 acc[4][4] = {};
    for (int kk = 0; kk < CC; kk += 32) {
        bf16x8 af[4], bfr[4];
        #pragma unroll
        for (int m = 0; m < 4; ++m)
            af[m] = *reinterpret_cast<const bf16x8*>(Ab + (size_t)(row0 + m*16 + lr)*CC + kk + lk);
        #pragma unroll
        for (int n = 0; n < 4; ++n)
            bfr[n] = *reinterpret_cast<const bf16x8*>(Bb + (size_t)(col0 + n*16 + lr)*CC + kk + lk);
        #pragma unroll
        for (int m = 0; m < 4; ++m)
            #pragma unroll
            for (int n = 0; n < 4; ++n)
                acc[m][n] = __builtin_amdgcn_mfma_f32_16x16x32_bf16(af[m], bfr[n], acc[m][n], 0, 0, 0);
    }

    int cr = (lane >> 4) * 4, ccol = lane & 15;
    int pm = (1 << LP) - 1;
    #pragma unroll
    for (int m = 0; m < 4; ++m) {
        #pragma unroll
        for (int n = 0; n < 4; ++n) {
            int colg = col0 + n*16 + ccol;
            int bh = colg >> LP, p = colg & pm;
            __hip_bfloat16* dst = Cc + (size_t)bh*8192 + poff + p;
            #pragma unroll
            for (int j = 0; j < 4; ++j) {
                int r = row0 + m*16 + cr + j;
                dst[r*16] = __float2bfloat16(acc[m][n][j]);
            }
        }
    }
}

// ---------------------------------------------------------------------------
// k_main v9: free-running waves. Each wave stages ONLY its own 8-channel LDS
// slice via global_load_lds (4-buffer ring, prefetch distance 3) and paces
// itself with counted vmcnt — NO per-tile barriers (waves share no x data).
// Only the softmax reduce at the pass boundary synchronizes (3 syncthreads).
// Pass-B vmcnt accounts for the 8 output stores in the queue.
// ---------------------------------------------------------------------------
template<int L>
__device__ __forceinline__ void softmax2(float2* a) {
    float mx = a[0].x, my = a[0].y;
    #pragma unroll
    for (int j = 1; j < L; ++j) { mx = fmaxf(mx, a[j].x); my = fmaxf(my, a[j].y); }
    float sx = 0.f, sy = 0.f;
    #pragma unroll
    for (int j = 0; j < L; ++j) {
        a[j].x = __expf(a[j].x - mx); sx += a[j].x;
        a[j].y = __expf(a[j].y - my); sy += a[j].y;
    }
    float rx = 1.f / sx, ry = 1.f / sy;
    #pragma unroll
    for (int j = 0; j < L; ++j) { a[j].x *= rx; a[j].y *= ry; }
}

__global__ __launch_bounds__(256, 4) void k_main(
    const float* __restrict__ x, const __hip_bfloat16* __restrict__ Cc,
    float* __restrict__ out)
{
    int bh = blockIdx.x;
    int b = bh >> 7, h = bh & 127;
    int t = threadIdx.x;
    int lane = t & 63;
    int wv = __builtin_amdgcn_readfirstlane(t >> 6);   // 0..3, wave-uniform
    const uint32_t* Cb = (const uint32_t*)(Cc + (size_t)bh*8192); // 8 dw / row
    const float* xg = x  + ((size_t)b*CC)*HW + h*128;  // + c*HW + w
    float*       og = out + ((size_t)b*CC)*HW + h*128;

    __shared__ float xbuf[4][32*128];                  // 65536 B
    __shared__ float att_sx[2][64][15];                // 7680 B
    __shared__ float att_sy[2][64][15];                // 7680 B

    float2 att[14];
    #pragma unroll
    for (int p = 0; p < 14; ++p) att[p] = make_float2(0.f, 0.f);

    // stage tile tt (channels (tt&7)*32, this wave's 8-channel slice) into
    // xbuf[tt&3]; 4 DMA (dwordx4) per wave — per-wave private region.
    auto STAGE = [&](int tt) {
        int cb = (tt & 7) * 32;
        float* bufp = xbuf[tt & 3];
        #pragma unroll
        for (int q = 0; q < 4; ++q) {
            int c0 = cb + wv*8 + q*2;
            const float* gp = xg + (size_t)(c0 + (lane >> 5))*HW + (lane & 31)*4;
            float* lp = &bufp[(wv*8 + q*2)*128];
            __builtin_amdgcn_global_load_lds((glb_u32_t*)gp, (lds_u32_t*)lp, 16, 0, 0);
        }
    };

    STAGE(0);
    STAGE(1);
    STAGE(2);

    #pragma unroll 1
    for (int tt = 0; tt < 16; ++tt) {
        if (tt == 8) {
            // ---- cross-wave att reduce + softmax (pass boundary) ----
            // (__syncthreads drains the DMA queue once; tiles 8..10 land.)
            if (wv >= 2) {
                #pragma unroll
                for (int p = 0; p < 14; ++p) {
                    att_sx[wv-2][lane][p] = att[p].x;
                    att_sy[wv-2][lane][p] = att[p].y;
                }
            }
            __syncthreads();
            if (wv < 2) {
                #pragma unroll
                for (int p = 0; p < 14; ++p) {
                    att[p].x += att_sx[wv][lane][p];
                    att[p].y += att_sy[wv][lane][p];
                }
                if (wv == 1) {
                    #pragma unroll
                    for (int p = 0; p < 14; ++p) {
                        att_sx[1][lane][p] = att[p].x;
                        att_sy[1][lane][p] = att[p].y;
                    }
                }
            }
            __syncthreads();
            if (wv == 0) {
                #pragma unroll
                for (int p = 0; p < 14; ++p) {
                    att[p].x = (att[p].x + att_sx[1][lane][p]) * 0.0625f;
                    att[p].y = (att[p].y + att_sy[1][lane][p]) * 0.0625f;
                }
                softmax2<2>(att + 0);
                softmax2<4>(att + 2);
                softmax2<8>(att + 6);
                #pragma unroll
                for (int p = 0; p < 14; ++p) {
                    att_sx[0][lane][p] = att[p].x;
                    att_sy[0][lane][p] = att[p].y;
                }
            }
            __syncthreads();
            #pragma unroll
            for (int p = 0; p < 14; ++p) {
                att[p].x = att_sx[0][lane][p];
                att[p].y = att_sy[0][lane][p];
            }
        }

        // ---- per-wave pacing: ensure tile tt's 4 DMAs have landed ----
        // pass A queue: DMA(tt..tt+2)=12 -> wait 8. pass B adds 8 stores of
        // tile tt-1 (older tiles' stores already forced out): steady 16;
        // tail tt=14 -> 12, tt=15 -> 8.
        if (tt < 8)       asm volatile("s_waitcnt vmcnt(8)"  ::: "memory");
        else if (tt < 14) asm volatile("s_waitcnt vmcnt(16)" ::: "memory");
        else if (tt == 14) asm volatile("s_waitcnt vmcnt(12)" ::: "memory");
        else               asm volatile("s_waitcnt vmcnt(8)"  ::: "memory");
        __builtin_amdgcn_sched_barrier(0);

        if (tt + 3 < 16) STAGE(tt + 3);

        // ---- consume tile tt (this wave's 8 channels) ----
        {
            int cb = (tt & 7) * 32;
            bool passB = (tt >= 8);
            const float* xb = &xbuf[tt & 3][(wv*8)*128];
            int crow = (passB ? 256 : 0) + cb + wv*8;
            const uint32_t* wr = Cb + (size_t)crow*8;
            #pragma unroll
            for (int half = 0; half < 2; ++half) {
                uint32_t u[4][7];
                #pragma unroll
                for (int q = 0; q < 4; ++q)
                    #pragma unroll
                    for (int j = 0; j < 7; ++j)
                        u[q][j] = wr[(half*4 + q)*8 + j];   // wave-uniform s_loads
                #pragma unroll
                for (int q = 0; q < 4; ++q) {
                    int qq = half*4 + q;
                    float2 xv = *(const float2*)&xb[qq*128 + lane*2];
                    if (!passB) {
                        #pragma unroll
                        for (int j = 0; j < 7; ++j) {
                            float mlo = __uint_as_float(u[q][j] << 16);
                            float mhi = __uint_as_float(u[q][j] & 0xFFFF0000u);
                            att[2*j].x   += xv.x * mlo;  att[2*j].y   += xv.y * mlo;
                            att[2*j+1].x += xv.x * mhi;  att[2*j+1].y += xv.y * mhi;
                        }
                    } else {
                        float2 acc = xv;                    // residual (exact fp32)
                        #pragma unroll
                        for (int j = 0; j < 7; ++j) {
                            float vlo = __uint_as_float(u[q][j] << 16);
                            float vhi = __uint_as_float(u[q][j] & 0xFFFF0000u);
                            acc.x += att[2*j].x * vlo;   acc.y += att[2*j].y * vlo;
                            acc.x += att[2*j+1].x * vhi; acc.y += att[2*j+1].y * vhi;
                        }
                        int o = cb + wv*8 + qq;
                        *(float2*)&og[(size_t)o*HW + lane*2] = acc;
                    }
                }
            }
        }
    }
}

// ---------------------------------------------------------------------------
extern "C" void kernel_launch(void* const* d_in, const int* in_sizes, int n_in,
                              void* d_out, int out_size, void* d_ws, size_t ws_size,
                              hipStream_t stream)
{
    (void)in_sizes; (void)n_in; (void)out_size; (void)ws_size;
    const float* x   = (const float*)d_in[0];
    const float* Wp  = (const float*)d_in[1];
    const float* Wf  = (const float*)d_in[2];
    const float* Wo  = (const float*)d_in[3];
    const float* Wfu = (const float*)d_in[4];
    float* out = (float*)d_out;

    // workspace layout (bytes):
    //   E     fp32 3*MAT          @ 0         =   786432
    //   A     bf16 3*512*256      @ 786432    =   786432
    //   Bt    bf16 28672*256      @ 1572864   = 14680064
    //   Cc    bf16 2048*512*16    @ 16252928  = 33554432
    //   (binsG fp32 16.8 MB aliases Cc: consumed by poolB before k_gemm)
    char* wsb = (char*)d_ws;
    float*          E     = (float*)wsb;
    __hip_bfloat16* A     = (__hip_bfloat16*)(wsb + 786432);
    __hip_bfloat16* Bt    = (__hip_bfloat16*)(wsb + 1572864);
    __hip_bfloat16* Cc    = (__hip_bfloat16*)(wsb + 16252928);
    float*          binsG = (float*)(wsb + 16252928);

    k_mats1<<<dim3(6*CC),  dim3(256), 0, stream>>>(Wp, Wf, Wo, Wfu, A, E);
    k_mats2<<<dim3(3*CC),  dim3(256), 0, stream>>>(Wp, E, A);
    k_poolA<<<dim3(4096),  dim3(256), 0, stream>>>(x, binsG);
    k_poolB<<<dim3(NBH),   dim3(256), 0, stream>>>(binsG, Bt);
    k_gemm <<<dim3(1792),  dim3(128), 0, stream>>>(A, Bt, Cc);
    k_main <<<dim3(NBH),   dim3(256), 0, stream>>>(x, Cc, out);
}